// Round 3
// baseline (4426.736 us; speedup 1.0000x reference)
//
#include <hip/hip_runtime.h>

#define NUM_NODES 100000
#define EMB_DIM   64
#define NUM_LAYERS 3
#define NUM_EDGES 3200000
#define NUM_QUERY 1000000

#define BSHIFT   6
#define BNODES   64                                    // nodes per bucket
#define NBUCKETS ((NUM_NODES + BNODES - 1) / BNODES)   // 1563
#define SRC_MASK 131071                                // 17 bits (NUM_NODES < 2^17)

// ---------------------------------------------------------------------------
// per-node degree histogram (int atomics, int4 loads)
__global__ void hist_kernel(const int4* __restrict__ dst4, int* __restrict__ deg) {
    int i = blockIdx.x * blockDim.x + threadIdx.x;
    int stride = gridDim.x * blockDim.x;
    for (; i < NUM_EDGES / 4; i += stride) {
        int4 d = dst4[i];
        atomicAdd(&deg[d.x], 1);
        atomicAdd(&deg[d.y], 1);
        atomicAdd(&deg[d.z], 1);
        atomicAdd(&deg[d.w], 1);
    }
}

// bucket counts: bcnt[b] = sum of deg over the bucket's 64 nodes (wave reduce)
__global__ void bktcnt_kernel(const int* __restrict__ deg, int* __restrict__ bcnt) {
    int gw   = (blockIdx.x * blockDim.x + threadIdx.x) >> 6;
    int lane = threadIdx.x & 63;
    if (gw >= NBUCKETS) return;
    int idx = (gw << BSHIFT) + lane;
    int v = (idx < NUM_NODES) ? deg[idx] : 0;
    #pragma unroll
    for (int o = 32; o > 0; o >>= 1) v += __shfl_xor(v, o);
    if (lane == 0) bcnt[gw] = v;
}

// single-block scan over NBUCKETS (2 tiles): boffs[b+1]=incl, cursor[b]=excl
__global__ void scan_kernel(const int* __restrict__ bcnt, int* __restrict__ boffs,
                            int* __restrict__ cursor) {
    __shared__ int tile[1024];
    __shared__ int carry;
    int t = threadIdx.x;
    if (t == 0) { carry = 0; boffs[0] = 0; }
    __syncthreads();
    for (int base = 0; base < NBUCKETS; base += 1024) {
        int v = (base + t < NBUCKETS) ? bcnt[base + t] : 0;
        tile[t] = v;
        __syncthreads();
        for (int d = 1; d < 1024; d <<= 1) {
            int add = (t >= d) ? tile[t - d] : 0;
            __syncthreads();
            tile[t] += add;
            __syncthreads();
        }
        int inc = tile[t] + carry;
        if (base + t < NBUCKETS) { boffs[base + t + 1] = inc; cursor[base + t] = inc - v; }
        __syncthreads();
        if (t == 1023) carry = inc;
        __syncthreads();
    }
}

// dis[n] = deg>0 ? rsqrt(deg) : 0
__global__ void dis_kernel(const int* __restrict__ deg, float* __restrict__ dis) {
    int i = blockIdx.x * blockDim.x + threadIdx.x;
    if (i < NUM_NODES) {
        int d = deg[i];
        dis[i] = (d > 0) ? rsqrtf((float)d) : 0.0f;
    }
}

// y = dis ⊙ emb (row-wise scale), float4 vectorized
__global__ void prescale_kernel(const float4* __restrict__ emb4, const float* __restrict__ dis,
                                float4* __restrict__ y4) {
    int i = blockIdx.x * blockDim.x + threadIdx.x;
    int stride = gridDim.x * blockDim.x;
    const int n4 = NUM_NODES * EMB_DIM / 4;
    for (; i < n4; i += stride) {
        float d = dis[i >> 4];               // 16 float4s per row
        float4 v = emb4[i];
        v.x *= d; v.y *= d; v.z *= d; v.w *= d;
        y4[i] = v;
    }
}

// coarse-bucket scatter: packed[pos] = src | (dst&63)<<17, grouped by dst>>6
__global__ void scatter_kernel(const int4* __restrict__ src4, const int4* __restrict__ dst4,
                               int* __restrict__ cursor, int* __restrict__ packed) {
    int i = blockIdx.x * blockDim.x + threadIdx.x;
    int stride = gridDim.x * blockDim.x;
    for (; i < NUM_EDGES / 4; i += stride) {
        int4 s = src4[i];
        int4 d = dst4[i];
        int p0 = atomicAdd(&cursor[d.x >> BSHIFT], 1); packed[p0] = s.x | ((d.x & 63) << 17);
        int p1 = atomicAdd(&cursor[d.y >> BSHIFT], 1); packed[p1] = s.y | ((d.y & 63) << 17);
        int p2 = atomicAdd(&cursor[d.z >> BSHIFT], 1); packed[p2] = s.z | ((d.z & 63) << 17);
        int p3 = atomicAdd(&cursor[d.w >> BSHIFT], 1); packed[p3] = s.w | ((d.w & 63) << 17);
    }
}

// ---------------------------------------------------------------------------
// Block per bucket; LDS accumulator [64 nodes][64 dims]; lane = dim.
// acc[dl] += y[src];  writeout: x = dis[node]*acc;
//  mode 0: yout = dis*x; outw = alpha*(emb + x)
//  mode 1: yout = dis*x; outw += alpha*x
//  mode 2:              outw += alpha*x
__global__ __launch_bounds__(256) void prop_kernel(
        const int* __restrict__ boffs, const int* __restrict__ packed,
        const float* __restrict__ dis, const float* __restrict__ yin,
        float* __restrict__ yout, const float* __restrict__ emb,
        float* __restrict__ outw, float alpha, int mode) {
    __shared__ float acc[BNODES * EMB_DIM];            // 16 KB
    int tid  = threadIdx.x;
    int lane = tid & 63;
    int wid  = tid >> 6;

    #pragma unroll
    for (int k = tid; k < BNODES * EMB_DIM; k += 256) acc[k] = 0.0f;
    __syncthreads();

    int beg = boffs[blockIdx.x];
    int end = boffs[blockIdx.x + 1];

    // full chunks of 64 edges, 4 waves round-robin, 4-edge unrolled inner loop
    int base = beg + (wid << 6);
    for (; base + 64 <= end; base += 256) {
        int p = packed[base + lane];
        #pragma unroll
        for (int t = 0; t < 64; t += 4) {
            int p0 = __shfl(p, t);
            int p1 = __shfl(p, t + 1);
            int p2 = __shfl(p, t + 2);
            int p3 = __shfl(p, t + 3);
            float v0 = yin[((p0 & SRC_MASK) << 6) + lane];
            float v1 = yin[((p1 & SRC_MASK) << 6) + lane];
            float v2 = yin[((p2 & SRC_MASK) << 6) + lane];
            float v3 = yin[((p3 & SRC_MASK) << 6) + lane];
            atomicAdd(&acc[((p0 >> 17) << 6) + lane], v0);
            atomicAdd(&acc[((p1 >> 17) << 6) + lane], v1);
            atomicAdd(&acc[((p2 >> 17) << 6) + lane], v2);
            atomicAdd(&acc[((p3 >> 17) << 6) + lane], v3);
        }
    }
    // tail chunk (<64 edges), at most one per bucket, owned by exactly one wave
    if (base < end) {
        int n = end - base;
        int p = (lane < n) ? packed[base + lane] : 0;
        for (int t = 0; t < n; ++t) {
            int pe = __shfl(p, t);
            float v = yin[((pe & SRC_MASK) << 6) + lane];
            atomicAdd(&acc[((pe >> 17) << 6) + lane], v);
        }
    }
    __syncthreads();

    int nodebase = blockIdx.x << BSHIFT;
    for (int r = wid; r < BNODES; r += 4) {
        int node = nodebase + r;
        if (node >= NUM_NODES) break;
        float dn = dis[node];
        float x  = dn * acc[(r << 6) + lane];          // x_{l+1}
        int o = (node << 6) + lane;
        if (mode == 0) {
            yout[o] = dn * x;
            outw[o] = alpha * (emb[o] + x);
        } else if (mode == 1) {
            yout[o] = dn * x;
            outw[o] += alpha * x;
        } else {
            outw[o] += alpha * x;
        }
    }
}

// One wave per query: res[q] = dot(out[a], out[b]) over 64 dims
__global__ void score_kernel(const int* __restrict__ qa, const int* __restrict__ qb,
                             const float* __restrict__ x, float* __restrict__ res) {
    int wid  = (blockIdx.x * blockDim.x + threadIdx.x) >> 6;
    int lane = threadIdx.x & 63;
    if (wid >= NUM_QUERY) return;
    int a = qa[wid];
    int b = qb[wid];
    float p = x[(a << 6) + lane] * x[(b << 6) + lane];
    #pragma unroll
    for (int off = 32; off > 0; off >>= 1) p += __shfl_xor(p, off);
    if (lane == 0) res[wid] = p;
}

extern "C" void kernel_launch(void* const* d_in, const int* in_sizes, int n_in,
                              void* d_out, int out_size, void* d_ws, size_t ws_size,
                              hipStream_t stream) {
    const float* emb  = (const float*)d_in[0];
    const int*   edge = (const int*)d_in[1];   // [2][NUM_EDGES]: src then dst
    const int*   qidx = (const int*)d_in[2];   // [2][NUM_QUERY]
    float*       out  = (float*)d_out;         // [NUM_QUERY]

    const int* e_src = edge;
    const int* e_dst = edge + NUM_EDGES;
    const int* q_a   = qidx;
    const int* q_b   = qidx + NUM_QUERY;

    const size_t XBYTES = (size_t)NUM_NODES * EMB_DIM * sizeof(float); // 25.6 MB
    char* ws = (char*)d_ws;
    size_t off = 0;
    auto carve = [&](size_t bytes) { void* p = ws + off; off += (bytes + 255) & ~(size_t)255; return p; };
    int*   deg_i   = (int*)  carve((size_t)NUM_NODES * 4);
    int*   bcnt    = (int*)  carve((size_t)NBUCKETS * 4);
    int*   boffs   = (int*)  carve((size_t)(NBUCKETS + 1) * 4);
    int*   cursor  = (int*)  carve((size_t)NBUCKETS * 4);
    float* dis     = (float*)carve((size_t)NUM_NODES * 4);
    int*   packed  = (int*)  carve((size_t)NUM_EDGES * 4);   // 12.8 MB
    float* yA      = (float*)carve(XBYTES);
    float* yB      = (float*)carve(XBYTES);
    float* outw    = (float*)carve(XBYTES);

    const float alpha = 1.0f / (NUM_LAYERS + 1);   // 0.25

    // ---- build coarse-bucketed edge list (dst>>6 buckets)
    hipMemsetAsync(deg_i, 0, (size_t)NUM_NODES * 4, stream);
    hist_kernel<<<2048, 256, 0, stream>>>((const int4*)e_dst, deg_i);
    bktcnt_kernel<<<(NBUCKETS * 64 + 255) / 256, 256, 0, stream>>>(deg_i, bcnt);
    scan_kernel<<<1, 1024, 0, stream>>>(bcnt, boffs, cursor);
    dis_kernel<<<(NUM_NODES + 255) / 256, 256, 0, stream>>>(deg_i, dis);
    prescale_kernel<<<2048, 256, 0, stream>>>((const float4*)emb, dis, (float4*)yA);
    scatter_kernel<<<2048, 256, 0, stream>>>((const int4*)e_src, (const int4*)e_dst,
                                             cursor, packed);

    // ---- 3 propagation layers (y-space: y = dis ⊙ x), out-accumulation fused
    prop_kernel<<<NBUCKETS, 256, 0, stream>>>(boffs, packed, dis, yA, yB, emb, outw, alpha, 0);
    prop_kernel<<<NBUCKETS, 256, 0, stream>>>(boffs, packed, dis, yB, yA, emb, outw, alpha, 1);
    prop_kernel<<<NBUCKETS, 256, 0, stream>>>(boffs, packed, dis, yA, yB, emb, outw, alpha, 2);

    // ---- scoring
    score_kernel<<<(NUM_QUERY + 3) / 4, 256, 0, stream>>>(q_a, q_b, outw, out);
}

// Round 4
// 1146.772 us; speedup vs baseline: 3.8602x; 3.8602x over previous
//
#include <hip/hip_runtime.h>

#define NUM_NODES 100000
#define EMB_DIM   64
#define NUM_LAYERS 3
#define NUM_EDGES 3200000
#define NUM_QUERY 1000000

#define BSHIFT   6
#define BNODES   64                                    // nodes per bucket
#define NBUCKETS ((NUM_NODES + BNODES - 1) / BNODES)   // 1563
#define SRC_MASK 131071                                // 17 bits (NUM_NODES < 2^17)

// ---------------------------------------------------------------------------
// per-node degree histogram (int atomics, int4 loads)
__global__ void hist_kernel(const int4* __restrict__ dst4, int* __restrict__ deg) {
    int i = blockIdx.x * blockDim.x + threadIdx.x;
    int stride = gridDim.x * blockDim.x;
    for (; i < NUM_EDGES / 4; i += stride) {
        int4 d = dst4[i];
        atomicAdd(&deg[d.x], 1);
        atomicAdd(&deg[d.y], 1);
        atomicAdd(&deg[d.z], 1);
        atomicAdd(&deg[d.w], 1);
    }
}

// bucket counts: bcnt[b] = sum of deg over the bucket's 64 nodes (wave reduce)
__global__ void bktcnt_kernel(const int* __restrict__ deg, int* __restrict__ bcnt) {
    int gw   = (blockIdx.x * blockDim.x + threadIdx.x) >> 6;
    int lane = threadIdx.x & 63;
    if (gw >= NBUCKETS) return;
    int idx = (gw << BSHIFT) + lane;
    int v = (idx < NUM_NODES) ? deg[idx] : 0;
    #pragma unroll
    for (int o = 32; o > 0; o >>= 1) v += __shfl_xor(v, o);
    if (lane == 0) bcnt[gw] = v;
}

// single-block scan over NBUCKETS (2 tiles): boffs[b+1]=incl, cursor[b]=excl
__global__ void scan_kernel(const int* __restrict__ bcnt, int* __restrict__ boffs,
                            int* __restrict__ cursor) {
    __shared__ int tile[1024];
    __shared__ int carry;
    int t = threadIdx.x;
    if (t == 0) { carry = 0; boffs[0] = 0; }
    __syncthreads();
    for (int base = 0; base < NBUCKETS; base += 1024) {
        int v = (base + t < NBUCKETS) ? bcnt[base + t] : 0;
        tile[t] = v;
        __syncthreads();
        for (int d = 1; d < 1024; d <<= 1) {
            int add = (t >= d) ? tile[t - d] : 0;
            __syncthreads();
            tile[t] += add;
            __syncthreads();
        }
        int inc = tile[t] + carry;
        if (base + t < NBUCKETS) { boffs[base + t + 1] = inc; cursor[base + t] = inc - v; }
        __syncthreads();
        if (t == 1023) carry = inc;
        __syncthreads();
    }
}

// dis[n] = deg>0 ? rsqrt(deg) : 0
__global__ void dis_kernel(const int* __restrict__ deg, float* __restrict__ dis) {
    int i = blockIdx.x * blockDim.x + threadIdx.x;
    if (i < NUM_NODES) {
        int d = deg[i];
        dis[i] = (d > 0) ? rsqrtf((float)d) : 0.0f;
    }
}

// y = dis ⊙ emb (row-wise scale), float4 vectorized
__global__ void prescale_kernel(const float4* __restrict__ emb4, const float* __restrict__ dis,
                                float4* __restrict__ y4) {
    int i = blockIdx.x * blockDim.x + threadIdx.x;
    int stride = gridDim.x * blockDim.x;
    const int n4 = NUM_NODES * EMB_DIM / 4;
    for (; i < n4; i += stride) {
        float d = dis[i >> 4];               // 16 float4s per row
        float4 v = emb4[i];
        v.x *= d; v.y *= d; v.z *= d; v.w *= d;
        y4[i] = v;
    }
}

// coarse-bucket scatter: packed[pos] = src | (dst&63)<<17, grouped by dst>>6
__global__ void scatter_kernel(const int4* __restrict__ src4, const int4* __restrict__ dst4,
                               int* __restrict__ cursor, int* __restrict__ packed) {
    int i = blockIdx.x * blockDim.x + threadIdx.x;
    int stride = gridDim.x * blockDim.x;
    for (; i < NUM_EDGES / 4; i += stride) {
        int4 s = src4[i];
        int4 d = dst4[i];
        int p0 = atomicAdd(&cursor[d.x >> BSHIFT], 1); packed[p0] = s.x | ((d.x & 63) << 17);
        int p1 = atomicAdd(&cursor[d.y >> BSHIFT], 1); packed[p1] = s.y | ((d.y & 63) << 17);
        int p2 = atomicAdd(&cursor[d.z >> BSHIFT], 1); packed[p2] = s.z | ((d.z & 63) << 17);
        int p3 = atomicAdd(&cursor[d.w >> BSHIFT], 1); packed[p3] = s.w | ((d.w & 63) << 17);
    }
}

// per-bucket local counting sort -> exact per-node CSR (src_srt, offs)
__global__ __launch_bounds__(256) void lsort_kernel(
        const int* __restrict__ boffs, const int* __restrict__ packed,
        int* __restrict__ offs, int* __restrict__ src_srt) {
    __shared__ int cnt[BNODES];
    int b   = blockIdx.x;
    int tid = threadIdx.x;
    int beg = boffs[b];
    int end = boffs[b + 1];
    if (tid < BNODES) cnt[tid] = 0;
    __syncthreads();
    for (int i = beg + tid; i < end; i += 256)
        atomicAdd(&cnt[(packed[i] >> 17) & 63], 1);
    __syncthreads();
    if (tid < 64) {                      // wave 0: exclusive scan of 64 counters
        int v = cnt[tid];
        int x = v;
        #pragma unroll
        for (int d = 1; d < 64; d <<= 1) {
            int y = __shfl_up(x, d);
            if (tid >= d) x += y;
        }
        int ex = x - v;                  // exclusive prefix
        int node = (b << BSHIFT) + tid;
        if (node <= NUM_NODES) offs[node] = beg + ex;  // last bucket's l=32 writes offs[N]=E
        cnt[tid] = ex;                   // reuse as local cursor
    }
    __syncthreads();
    for (int i = beg + tid; i < end; i += 256) {
        int p  = packed[i];
        int dl = (p >> 17) & 63;
        int pos = beg + atomicAdd(&cnt[dl], 1);
        src_srt[pos] = p & SRC_MASK;
    }
}

// ---------------------------------------------------------------------------
// Wave per node, lane = dim, exact CSR gather, zero atomics, y-space.
// acc = sum_{s in N(t)} yin[s];  x_{l+1} = dis_t*acc;  y_{l+1} = dis_t^2*acc
//  mode 0: yout = dn*dn*acc; outw = alpha*(emb + dn*acc)
//  mode 1: yout = dn*dn*acc; outw += alpha*dn*acc
//  mode 2:                   outw += alpha*dn*acc
__global__ __launch_bounds__(256) void prop_kernel(
        const int* __restrict__ offs, const int* __restrict__ src_s,
        const float* __restrict__ dis, const float* __restrict__ yin,
        float* __restrict__ yout, const float* __restrict__ emb,
        float* __restrict__ outw, float alpha, int mode) {
    int wid  = (blockIdx.x * blockDim.x + threadIdx.x) >> 6;
    int lane = threadIdx.x & 63;
    if (wid >= NUM_NODES) return;
    int beg = offs[wid];
    int end = offs[wid + 1];
    float acc = 0.0f;
    int j = beg;
    // 8-deep gather pipeline
    for (; j + 8 <= end; j += 8) {
        int s0 = src_s[j];     int s1 = src_s[j + 1];
        int s2 = src_s[j + 2]; int s3 = src_s[j + 3];
        int s4 = src_s[j + 4]; int s5 = src_s[j + 5];
        int s6 = src_s[j + 6]; int s7 = src_s[j + 7];
        float v0 = yin[(s0 << 6) + lane];
        float v1 = yin[(s1 << 6) + lane];
        float v2 = yin[(s2 << 6) + lane];
        float v3 = yin[(s3 << 6) + lane];
        float v4 = yin[(s4 << 6) + lane];
        float v5 = yin[(s5 << 6) + lane];
        float v6 = yin[(s6 << 6) + lane];
        float v7 = yin[(s7 << 6) + lane];
        acc += ((v0 + v1) + (v2 + v3)) + ((v4 + v5) + (v6 + v7));
    }
    for (; j < end; ++j) acc += yin[(src_s[j] << 6) + lane];

    float dn = dis[wid];
    float x  = dn * acc;                 // x_{l+1}
    int o = (wid << 6) + lane;
    if (mode == 0) {
        yout[o] = dn * x;
        outw[o] = alpha * (emb[o] + x);
    } else if (mode == 1) {
        yout[o] = dn * x;
        outw[o] += alpha * x;
    } else {
        outw[o] += alpha * x;
    }
}

// One wave per query: res[q] = dot(out[a], out[b]) over 64 dims
__global__ void score_kernel(const int* __restrict__ qa, const int* __restrict__ qb,
                             const float* __restrict__ x, float* __restrict__ res) {
    int wid  = (blockIdx.x * blockDim.x + threadIdx.x) >> 6;
    int lane = threadIdx.x & 63;
    if (wid >= NUM_QUERY) return;
    int a = qa[wid];
    int b = qb[wid];
    float p = x[(a << 6) + lane] * x[(b << 6) + lane];
    #pragma unroll
    for (int off = 32; off > 0; off >>= 1) p += __shfl_xor(p, off);
    if (lane == 0) res[wid] = p;
}

extern "C" void kernel_launch(void* const* d_in, const int* in_sizes, int n_in,
                              void* d_out, int out_size, void* d_ws, size_t ws_size,
                              hipStream_t stream) {
    const float* emb  = (const float*)d_in[0];
    const int*   edge = (const int*)d_in[1];   // [2][NUM_EDGES]: src then dst
    const int*   qidx = (const int*)d_in[2];   // [2][NUM_QUERY]
    float*       out  = (float*)d_out;         // [NUM_QUERY]

    const int* e_src = edge;
    const int* e_dst = edge + NUM_EDGES;
    const int* q_a   = qidx;
    const int* q_b   = qidx + NUM_QUERY;

    const size_t XBYTES = (size_t)NUM_NODES * EMB_DIM * sizeof(float); // 25.6 MB
    char* ws = (char*)d_ws;
    size_t off = 0;
    auto carve = [&](size_t bytes) { void* p = ws + off; off += (bytes + 255) & ~(size_t)255; return p; };
    int*   deg_i   = (int*)  carve((size_t)NUM_NODES * 4);
    int*   bcnt    = (int*)  carve((size_t)NBUCKETS * 4);
    int*   boffs   = (int*)  carve((size_t)(NBUCKETS + 1) * 4);
    int*   cursor  = (int*)  carve((size_t)NBUCKETS * 4);
    int*   offs    = (int*)  carve((size_t)(NUM_NODES + 1) * 4);
    float* dis     = (float*)carve((size_t)NUM_NODES * 4);
    int*   packed  = (int*)  carve((size_t)NUM_EDGES * 4);   // 12.8 MB
    int*   src_srt = (int*)  carve((size_t)NUM_EDGES * 4);   // 12.8 MB
    float* yA      = (float*)carve(XBYTES);
    float* yB      = (float*)carve(XBYTES);
    float* outw    = (float*)carve(XBYTES);

    const float alpha = 1.0f / (NUM_LAYERS + 1);   // 0.25

    // ---- build exact dst-sorted CSR via coarse buckets + local counting sort
    hipMemsetAsync(deg_i, 0, (size_t)NUM_NODES * 4, stream);
    hist_kernel<<<2048, 256, 0, stream>>>((const int4*)e_dst, deg_i);
    bktcnt_kernel<<<(NBUCKETS * 64 + 255) / 256, 256, 0, stream>>>(deg_i, bcnt);
    scan_kernel<<<1, 1024, 0, stream>>>(bcnt, boffs, cursor);
    dis_kernel<<<(NUM_NODES + 255) / 256, 256, 0, stream>>>(deg_i, dis);
    prescale_kernel<<<2048, 256, 0, stream>>>((const float4*)emb, dis, (float4*)yA);
    scatter_kernel<<<2048, 256, 0, stream>>>((const int4*)e_src, (const int4*)e_dst,
                                             cursor, packed);
    lsort_kernel<<<NBUCKETS, 256, 0, stream>>>(boffs, packed, offs, src_srt);

    // ---- 3 propagation layers (y-space), out-accumulation fused
    const int PROP_BLOCKS = (NUM_NODES * 64 + 255) / 256;
    prop_kernel<<<PROP_BLOCKS, 256, 0, stream>>>(offs, src_srt, dis, yA, yB, emb, outw, alpha, 0);
    prop_kernel<<<PROP_BLOCKS, 256, 0, stream>>>(offs, src_srt, dis, yB, yA, emb, outw, alpha, 1);
    prop_kernel<<<PROP_BLOCKS, 256, 0, stream>>>(offs, src_srt, dis, yA, yB, emb, outw, alpha, 2);

    // ---- scoring
    score_kernel<<<(NUM_QUERY + 3) / 4, 256, 0, stream>>>(q_a, q_b, outw, out);
}

// Round 5
// 607.983 us; speedup vs baseline: 7.2810x; 1.8862x over previous
//
#include <hip/hip_runtime.h>

#define NUM_NODES 100000
#define EMB_DIM   64
#define NUM_LAYERS 3
#define NUM_EDGES 3200000
#define NUM_QUERY 1000000

#define BSHIFT   6
#define BNODES   64                                    // nodes per bucket
#define NBUCKETS ((NUM_NODES + BNODES - 1) / BNODES)   // 1563
#define SRC_MASK 131071                                // 17 bits (NUM_NODES < 2^17)
#define NCHUNK   128
#define CHUNK    (NUM_EDGES / NCHUNK)                  // 25000 edges per chunk

// ---------------------------------------------------------------------------
// Pass 1: per-chunk bucket histogram in LDS -> hist_g[chunk][bucket]
__global__ __launch_bounds__(256) void chist_kernel(const int* __restrict__ dst,
                                                    int* __restrict__ hist_g) {
    __shared__ int h[NBUCKETS];
    int b = blockIdx.x, tid = threadIdx.x;
    for (int k = tid; k < NBUCKETS; k += 256) h[k] = 0;
    __syncthreads();
    int beg = b * CHUNK, end = beg + CHUNK;
    for (int i = beg + tid; i < end; i += 256)
        atomicAdd(&h[dst[i] >> BSHIFT], 1);
    __syncthreads();
    for (int k = tid; k < NBUCKETS; k += 256)
        hist_g[b * NBUCKETS + k] = h[k];
}

// Per-bucket exclusive scan across the 128 chunks (one wave per bucket, in place).
// Also emits bucket totals.
__global__ void bscan_kernel(int* __restrict__ hist_g, int* __restrict__ bcnt) {
    int gw   = (blockIdx.x * blockDim.x + threadIdx.x) >> 6;
    int lane = threadIdx.x & 63;
    if (gw >= NBUCKETS) return;
    int c0 = 2 * lane, c1 = 2 * lane + 1;
    int v0 = hist_g[c0 * NBUCKETS + gw];
    int v1 = hist_g[c1 * NBUCKETS + gw];
    int pair = v0 + v1, x = pair;
    #pragma unroll
    for (int d = 1; d < 64; d <<= 1) {
        int y = __shfl_up(x, d);
        if (lane >= d) x += y;
    }
    int ex = x - pair;                    // exclusive prefix over chunks
    hist_g[c0 * NBUCKETS + gw] = ex;
    hist_g[c1 * NBUCKETS + gw] = ex + v0;
    if (lane == 63) bcnt[gw] = x;         // bucket total
}

// single-block scan over NBUCKETS (2 tiles): boffs[b+1] = inclusive sum
__global__ void scan_kernel(const int* __restrict__ bcnt, int* __restrict__ boffs) {
    __shared__ int tile[1024];
    __shared__ int carry;
    int t = threadIdx.x;
    if (t == 0) { carry = 0; boffs[0] = 0; }
    __syncthreads();
    for (int base = 0; base < NBUCKETS; base += 1024) {
        int v = (base + t < NBUCKETS) ? bcnt[base + t] : 0;
        tile[t] = v;
        __syncthreads();
        for (int d = 1; d < 1024; d <<= 1) {
            int add = (t >= d) ? tile[t - d] : 0;
            __syncthreads();
            tile[t] += add;
            __syncthreads();
        }
        int inc = tile[t] + carry;
        if (base + t < NBUCKETS) boffs[base + t + 1] = inc;
        __syncthreads();
        if (t == 1023) carry = inc;
        __syncthreads();
    }
}

// Pass 2: scatter via LDS cursors — every (chunk,bucket) segment is written by
// exactly one block (one XCD), killing cross-XCD line ping-pong.
__global__ __launch_bounds__(256) void cscatter_kernel(
        const int* __restrict__ src, const int* __restrict__ dst,
        const int* __restrict__ boffs, const int* __restrict__ hist_g,
        int* __restrict__ packed) {
    __shared__ int cur[NBUCKETS];
    int b = blockIdx.x, tid = threadIdx.x;
    for (int k = tid; k < NBUCKETS; k += 256)
        cur[k] = boffs[k] + hist_g[b * NBUCKETS + k];
    __syncthreads();
    int beg = b * CHUNK, end = beg + CHUNK;
    for (int i = beg + tid; i < end; i += 256) {
        int s = src[i], d = dst[i];
        int pos = atomicAdd(&cur[d >> BSHIFT], 1);
        packed[pos] = s | ((d & 63) << 17);
    }
}

// per-bucket local counting sort -> exact per-node CSR (src_srt, offs) + dis
__global__ __launch_bounds__(256) void lsort_kernel(
        const int* __restrict__ boffs, const int* __restrict__ packed,
        int* __restrict__ offs, int* __restrict__ src_srt, float* __restrict__ dis) {
    __shared__ int cnt[BNODES];
    int b   = blockIdx.x;
    int tid = threadIdx.x;
    int beg = boffs[b];
    int end = boffs[b + 1];
    if (tid < BNODES) cnt[tid] = 0;
    __syncthreads();
    for (int i = beg + tid; i < end; i += 256)
        atomicAdd(&cnt[(packed[i] >> 17) & 63], 1);
    __syncthreads();
    if (tid < 64) {                      // wave 0: exclusive scan of 64 counters
        int v = cnt[tid];
        int x = v;
        #pragma unroll
        for (int d = 1; d < 64; d <<= 1) {
            int y = __shfl_up(x, d);
            if (tid >= d) x += y;
        }
        int ex = x - v;                  // exclusive prefix
        int node = (b << BSHIFT) + tid;
        if (node <= NUM_NODES) offs[node] = beg + ex;   // bucket 1562/tid 32 writes offs[N]=E
        if (node <  NUM_NODES) dis[node] = (v > 0) ? rsqrtf((float)v) : 0.0f;
        cnt[tid] = ex;                   // reuse as local cursor
    }
    __syncthreads();
    for (int i = beg + tid; i < end; i += 256) {
        int p  = packed[i];
        int pos = beg + atomicAdd(&cnt[(p >> 17) & 63], 1);
        src_srt[pos] = p & SRC_MASK;
    }
}

// y = dis ⊙ emb (row-wise scale), float4 vectorized
__global__ void prescale_kernel(const float4* __restrict__ emb4, const float* __restrict__ dis,
                                float4* __restrict__ y4) {
    int i = blockIdx.x * blockDim.x + threadIdx.x;
    int stride = gridDim.x * blockDim.x;
    const int n4 = NUM_NODES * EMB_DIM / 4;
    for (; i < n4; i += stride) {
        float d = dis[i >> 4];               // 16 float4s per row
        float4 v = emb4[i];
        v.x *= d; v.y *= d; v.z *= d; v.w *= d;
        y4[i] = v;
    }
}

// ---------------------------------------------------------------------------
// Wave per node, lane = dim, exact CSR gather, zero atomics, y-space.
//  mode 0: yout = dn*dn*acc; outw = alpha*(emb + dn*acc)
//  mode 1: yout = dn*dn*acc; outw += alpha*dn*acc
//  mode 2:                   outw += alpha*dn*acc
__global__ __launch_bounds__(256) void prop_kernel(
        const int* __restrict__ offs, const int* __restrict__ src_s,
        const float* __restrict__ dis, const float* __restrict__ yin,
        float* __restrict__ yout, const float* __restrict__ emb,
        float* __restrict__ outw, float alpha, int mode) {
    int wid  = (blockIdx.x * blockDim.x + threadIdx.x) >> 6;
    int lane = threadIdx.x & 63;
    if (wid >= NUM_NODES) return;
    int beg = offs[wid];
    int end = offs[wid + 1];
    float acc = 0.0f;
    int j = beg;
    // 8-deep gather pipeline
    for (; j + 8 <= end; j += 8) {
        int s0 = src_s[j];     int s1 = src_s[j + 1];
        int s2 = src_s[j + 2]; int s3 = src_s[j + 3];
        int s4 = src_s[j + 4]; int s5 = src_s[j + 5];
        int s6 = src_s[j + 6]; int s7 = src_s[j + 7];
        float v0 = yin[(s0 << 6) + lane];
        float v1 = yin[(s1 << 6) + lane];
        float v2 = yin[(s2 << 6) + lane];
        float v3 = yin[(s3 << 6) + lane];
        float v4 = yin[(s4 << 6) + lane];
        float v5 = yin[(s5 << 6) + lane];
        float v6 = yin[(s6 << 6) + lane];
        float v7 = yin[(s7 << 6) + lane];
        acc += ((v0 + v1) + (v2 + v3)) + ((v4 + v5) + (v6 + v7));
    }
    for (; j < end; ++j) acc += yin[(src_s[j] << 6) + lane];

    float dn = dis[wid];
    float x  = dn * acc;                 // x_{l+1}
    int o = (wid << 6) + lane;
    if (mode == 0) {
        yout[o] = dn * x;
        outw[o] = alpha * (emb[o] + x);
    } else if (mode == 1) {
        yout[o] = dn * x;
        outw[o] += alpha * x;
    } else {
        outw[o] += alpha * x;
    }
}

// One wave per query: res[q] = dot(out[a], out[b]) over 64 dims
__global__ void score_kernel(const int* __restrict__ qa, const int* __restrict__ qb,
                             const float* __restrict__ x, float* __restrict__ res) {
    int wid  = (blockIdx.x * blockDim.x + threadIdx.x) >> 6;
    int lane = threadIdx.x & 63;
    if (wid >= NUM_QUERY) return;
    int a = qa[wid];
    int b = qb[wid];
    float p = x[(a << 6) + lane] * x[(b << 6) + lane];
    #pragma unroll
    for (int off = 32; off > 0; off >>= 1) p += __shfl_xor(p, off);
    if (lane == 0) res[wid] = p;
}

extern "C" void kernel_launch(void* const* d_in, const int* in_sizes, int n_in,
                              void* d_out, int out_size, void* d_ws, size_t ws_size,
                              hipStream_t stream) {
    const float* emb  = (const float*)d_in[0];
    const int*   edge = (const int*)d_in[1];   // [2][NUM_EDGES]: src then dst
    const int*   qidx = (const int*)d_in[2];   // [2][NUM_QUERY]
    float*       out  = (float*)d_out;         // [NUM_QUERY]

    const int* e_src = edge;
    const int* e_dst = edge + NUM_EDGES;
    const int* q_a   = qidx;
    const int* q_b   = qidx + NUM_QUERY;

    const size_t XBYTES = (size_t)NUM_NODES * EMB_DIM * sizeof(float); // 25.6 MB
    char* ws = (char*)d_ws;
    size_t off = 0;
    auto carve = [&](size_t bytes) { void* p = ws + off; off += (bytes + 255) & ~(size_t)255; return p; };
    int*   hist_g  = (int*)  carve((size_t)NCHUNK * NBUCKETS * 4);   // 800 KB
    int*   bcnt    = (int*)  carve((size_t)NBUCKETS * 4);
    int*   boffs   = (int*)  carve((size_t)(NBUCKETS + 1) * 4);
    int*   offs    = (int*)  carve((size_t)(NUM_NODES + 1) * 4);
    float* dis     = (float*)carve((size_t)NUM_NODES * 4);
    int*   packed  = (int*)  carve((size_t)NUM_EDGES * 4);   // 12.8 MB
    int*   src_srt = (int*)  carve((size_t)NUM_EDGES * 4);   // 12.8 MB
    float* yA      = (float*)carve(XBYTES);
    float* yB      = (float*)carve(XBYTES);
    float* outw    = (float*)carve(XBYTES);

    const float alpha = 1.0f / (NUM_LAYERS + 1);   // 0.25

    // ---- build exact dst-sorted CSR: chunked counting sort, zero global atomics
    chist_kernel<<<NCHUNK, 256, 0, stream>>>(e_dst, hist_g);
    bscan_kernel<<<(NBUCKETS * 64 + 255) / 256, 256, 0, stream>>>(hist_g, bcnt);
    scan_kernel<<<1, 1024, 0, stream>>>(bcnt, boffs);
    cscatter_kernel<<<NCHUNK, 256, 0, stream>>>(e_src, e_dst, boffs, hist_g, packed);
    lsort_kernel<<<NBUCKETS, 256, 0, stream>>>(boffs, packed, offs, src_srt, dis);
    prescale_kernel<<<2048, 256, 0, stream>>>((const float4*)emb, dis, (float4*)yA);

    // ---- 3 propagation layers (y-space), out-accumulation fused
    const int PROP_BLOCKS = (NUM_NODES * 64 + 255) / 256;
    prop_kernel<<<PROP_BLOCKS, 256, 0, stream>>>(offs, src_srt, dis, yA, yB, emb, outw, alpha, 0);
    prop_kernel<<<PROP_BLOCKS, 256, 0, stream>>>(offs, src_srt, dis, yB, yA, emb, outw, alpha, 1);
    prop_kernel<<<PROP_BLOCKS, 256, 0, stream>>>(offs, src_srt, dis, yA, yB, emb, outw, alpha, 2);

    // ---- scoring
    score_kernel<<<(NUM_QUERY + 3) / 4, 256, 0, stream>>>(q_a, q_b, outw, out);
}

// Round 6
// 512.279 us; speedup vs baseline: 8.6413x; 1.1868x over previous
//
#include <hip/hip_runtime.h>

#define NUM_NODES 100000
#define EMB_DIM   64
#define NUM_LAYERS 3
#define NUM_EDGES 3200000
#define NUM_QUERY 1000000

#define BSHIFT   6
#define BNODES   64                                    // nodes per bucket
#define NBUCKETS ((NUM_NODES + BNODES - 1) / BNODES)   // 1563
#define SRC_MASK 131071                                // 17 bits (NUM_NODES < 2^17)
#define NCHUNK   128
#define CHUNK    (NUM_EDGES / NCHUNK)                  // 25000 edges per chunk

// ---------------------------------------------------------------------------
// Pass 1: per-chunk bucket histogram in LDS -> hist_g[chunk][bucket]
__global__ __launch_bounds__(256) void chist_kernel(const int* __restrict__ dst,
                                                    int* __restrict__ hist_g) {
    __shared__ int h[NBUCKETS];
    int b = blockIdx.x, tid = threadIdx.x;
    for (int k = tid; k < NBUCKETS; k += 256) h[k] = 0;
    __syncthreads();
    int beg = b * CHUNK, end = beg + CHUNK;
    for (int i = beg + tid; i < end; i += 256)
        atomicAdd(&h[dst[i] >> BSHIFT], 1);
    __syncthreads();
    for (int k = tid; k < NBUCKETS; k += 256)
        hist_g[b * NBUCKETS + k] = h[k];
}

// Per-bucket exclusive scan across the 128 chunks (one wave per bucket, in place).
// Also emits bucket totals.
__global__ void bscan_kernel(int* __restrict__ hist_g, int* __restrict__ bcnt) {
    int gw   = (blockIdx.x * blockDim.x + threadIdx.x) >> 6;
    int lane = threadIdx.x & 63;
    if (gw >= NBUCKETS) return;
    int c0 = 2 * lane, c1 = 2 * lane + 1;
    int v0 = hist_g[c0 * NBUCKETS + gw];
    int v1 = hist_g[c1 * NBUCKETS + gw];
    int pair = v0 + v1, x = pair;
    #pragma unroll
    for (int d = 1; d < 64; d <<= 1) {
        int y = __shfl_up(x, d);
        if (lane >= d) x += y;
    }
    int ex = x - pair;                    // exclusive prefix over chunks
    hist_g[c0 * NBUCKETS + gw] = ex;
    hist_g[c1 * NBUCKETS + gw] = ex + v0;
    if (lane == 63) bcnt[gw] = x;         // bucket total
}

// single-block scan over NBUCKETS (2 tiles): boffs[b+1] = inclusive sum
__global__ void scan_kernel(const int* __restrict__ bcnt, int* __restrict__ boffs) {
    __shared__ int tile[1024];
    __shared__ int carry;
    int t = threadIdx.x;
    if (t == 0) { carry = 0; boffs[0] = 0; }
    __syncthreads();
    for (int base = 0; base < NBUCKETS; base += 1024) {
        int v = (base + t < NBUCKETS) ? bcnt[base + t] : 0;
        tile[t] = v;
        __syncthreads();
        for (int d = 1; d < 1024; d <<= 1) {
            int add = (t >= d) ? tile[t - d] : 0;
            __syncthreads();
            tile[t] += add;
            __syncthreads();
        }
        int inc = tile[t] + carry;
        if (base + t < NBUCKETS) boffs[base + t + 1] = inc;
        __syncthreads();
        if (t == 1023) carry = inc;
        __syncthreads();
    }
}

// Pass 2: scatter via LDS cursors — every (chunk,bucket) segment is written by
// exactly one block (one XCD), killing cross-XCD line ping-pong.
__global__ __launch_bounds__(256) void cscatter_kernel(
        const int* __restrict__ src, const int* __restrict__ dst,
        const int* __restrict__ boffs, const int* __restrict__ hist_g,
        int* __restrict__ packed) {
    __shared__ int cur[NBUCKETS];
    int b = blockIdx.x, tid = threadIdx.x;
    for (int k = tid; k < NBUCKETS; k += 256)
        cur[k] = boffs[k] + hist_g[b * NBUCKETS + k];
    __syncthreads();
    int beg = b * CHUNK, end = beg + CHUNK;
    for (int i = beg + tid; i < end; i += 256) {
        int s = src[i], d = dst[i];
        int pos = atomicAdd(&cur[d >> BSHIFT], 1);
        packed[pos] = s | ((d & 63) << 17);
    }
}

// per-bucket local counting sort -> exact per-node CSR (src_srt, offs) + dis
__global__ __launch_bounds__(256) void lsort_kernel(
        const int* __restrict__ boffs, const int* __restrict__ packed,
        int* __restrict__ offs, int* __restrict__ src_srt, float* __restrict__ dis) {
    __shared__ int cnt[BNODES];
    int b   = blockIdx.x;
    int tid = threadIdx.x;
    int beg = boffs[b];
    int end = boffs[b + 1];
    if (tid < BNODES) cnt[tid] = 0;
    __syncthreads();
    for (int i = beg + tid; i < end; i += 256)
        atomicAdd(&cnt[(packed[i] >> 17) & 63], 1);
    __syncthreads();
    if (tid < 64) {                      // wave 0: exclusive scan of 64 counters
        int v = cnt[tid];
        int x = v;
        #pragma unroll
        for (int d = 1; d < 64; d <<= 1) {
            int y = __shfl_up(x, d);
            if (tid >= d) x += y;
        }
        int ex = x - v;                  // exclusive prefix
        int node = (b << BSHIFT) + tid;
        if (node <= NUM_NODES) offs[node] = beg + ex;   // bucket 1562/tid 32 writes offs[N]=E
        if (node <  NUM_NODES) dis[node] = (v > 0) ? rsqrtf((float)v) : 0.0f;
        cnt[tid] = ex;                   // reuse as local cursor
    }
    __syncthreads();
    for (int i = beg + tid; i < end; i += 256) {
        int p  = packed[i];
        int pos = beg + atomicAdd(&cnt[(p >> 17) & 63], 1);
        src_srt[pos] = p & SRC_MASK;
    }
}

// y = dis ⊙ emb (row-wise scale), float4 vectorized
__global__ void prescale_kernel(const float4* __restrict__ emb4, const float* __restrict__ dis,
                                float4* __restrict__ y4) {
    int i = blockIdx.x * blockDim.x + threadIdx.x;
    int stride = gridDim.x * blockDim.x;
    const int n4 = NUM_NODES * EMB_DIM / 4;
    for (; i < n4; i += stride) {
        float d = dis[i >> 4];               // 16 float4s per row
        float4 v = emb4[i];
        v.x *= d; v.y *= d; v.z *= d; v.w *= d;
        y4[i] = v;
    }
}

// ---------------------------------------------------------------------------
// Wave per node, lane = dim, exact CSR gather, zero atomics, y-space.
//  mode 0: yout = dn*dn*acc; outw = alpha*(emb + dn*acc)
//  mode 1: yout = dn*dn*acc; outw += alpha*dn*acc
//  mode 2:                   outw += alpha*dn*acc
__global__ __launch_bounds__(256) void prop_kernel(
        const int* __restrict__ offs, const int* __restrict__ src_s,
        const float* __restrict__ dis, const float* __restrict__ yin,
        float* __restrict__ yout, const float* __restrict__ emb,
        float* __restrict__ outw, float alpha, int mode) {
    int wid  = (blockIdx.x * blockDim.x + threadIdx.x) >> 6;
    int lane = threadIdx.x & 63;
    if (wid >= NUM_NODES) return;
    int beg = offs[wid];
    int end = offs[wid + 1];
    float acc = 0.0f;
    int j = beg;
    // 8-deep gather pipeline
    for (; j + 8 <= end; j += 8) {
        int s0 = src_s[j];     int s1 = src_s[j + 1];
        int s2 = src_s[j + 2]; int s3 = src_s[j + 3];
        int s4 = src_s[j + 4]; int s5 = src_s[j + 5];
        int s6 = src_s[j + 6]; int s7 = src_s[j + 7];
        float v0 = yin[(s0 << 6) + lane];
        float v1 = yin[(s1 << 6) + lane];
        float v2 = yin[(s2 << 6) + lane];
        float v3 = yin[(s3 << 6) + lane];
        float v4 = yin[(s4 << 6) + lane];
        float v5 = yin[(s5 << 6) + lane];
        float v6 = yin[(s6 << 6) + lane];
        float v7 = yin[(s7 << 6) + lane];
        acc += ((v0 + v1) + (v2 + v3)) + ((v4 + v5) + (v6 + v7));
    }
    for (; j < end; ++j) acc += yin[(src_s[j] << 6) + lane];

    float dn = dis[wid];
    float x  = dn * acc;                 // x_{l+1}
    int o = (wid << 6) + lane;
    if (mode == 0) {
        yout[o] = dn * x;
        outw[o] = alpha * (emb[o] + x);
    } else if (mode == 1) {
        yout[o] = dn * x;
        outw[o] += alpha * x;
    } else {
        outw[o] += alpha * x;
    }
}

// 16 queries per wave, 4 lanes per query, float4 row loads.
// Lane group g=lane>>2 owns query q = wave*16+g; k=lane&3 walks the row.
__global__ __launch_bounds__(256) void score_kernel(
        const int* __restrict__ qa, const int* __restrict__ qb,
        const float4* __restrict__ x4, float* __restrict__ res) {
    int wave = (blockIdx.x * blockDim.x + threadIdx.x) >> 6;
    int lane = threadIdx.x & 63;
    int g = lane >> 2;                   // query slot in wave (0..15)
    int k = lane & 3;                    // chunk lane (0..3)
    int q = (wave << 4) + g;
    int a = qa[q];
    int b = qb[q];
    const float4* pa = x4 + (a << 4);    // 16 float4s per row
    const float4* pb = x4 + (b << 4);
    float4 a0 = pa[k];      float4 b0 = pb[k];
    float4 a1 = pa[4 + k];  float4 b1 = pb[4 + k];
    float4 a2 = pa[8 + k];  float4 b2 = pb[8 + k];
    float4 a3 = pa[12 + k]; float4 b3 = pb[12 + k];
    float p = a0.x * b0.x;
    p = fmaf(a0.y, b0.y, p); p = fmaf(a0.z, b0.z, p); p = fmaf(a0.w, b0.w, p);
    p = fmaf(a1.x, b1.x, p); p = fmaf(a1.y, b1.y, p);
    p = fmaf(a1.z, b1.z, p); p = fmaf(a1.w, b1.w, p);
    p = fmaf(a2.x, b2.x, p); p = fmaf(a2.y, b2.y, p);
    p = fmaf(a2.z, b2.z, p); p = fmaf(a2.w, b2.w, p);
    p = fmaf(a3.x, b3.x, p); p = fmaf(a3.y, b3.y, p);
    p = fmaf(a3.z, b3.z, p); p = fmaf(a3.w, b3.w, p);
    p += __shfl_xor(p, 1);
    p += __shfl_xor(p, 2);
    if (k == 0) res[q] = p;
}

extern "C" void kernel_launch(void* const* d_in, const int* in_sizes, int n_in,
                              void* d_out, int out_size, void* d_ws, size_t ws_size,
                              hipStream_t stream) {
    const float* emb  = (const float*)d_in[0];
    const int*   edge = (const int*)d_in[1];   // [2][NUM_EDGES]: src then dst
    const int*   qidx = (const int*)d_in[2];   // [2][NUM_QUERY]
    float*       out  = (float*)d_out;         // [NUM_QUERY]

    const int* e_src = edge;
    const int* e_dst = edge + NUM_EDGES;
    const int* q_a   = qidx;
    const int* q_b   = qidx + NUM_QUERY;

    const size_t XBYTES = (size_t)NUM_NODES * EMB_DIM * sizeof(float); // 25.6 MB
    char* ws = (char*)d_ws;
    size_t off = 0;
    auto carve = [&](size_t bytes) { void* p = ws + off; off += (bytes + 255) & ~(size_t)255; return p; };
    int*   hist_g  = (int*)  carve((size_t)NCHUNK * NBUCKETS * 4);   // 800 KB
    int*   bcnt    = (int*)  carve((size_t)NBUCKETS * 4);
    int*   boffs   = (int*)  carve((size_t)(NBUCKETS + 1) * 4);
    int*   offs    = (int*)  carve((size_t)(NUM_NODES + 1) * 4);
    float* dis     = (float*)carve((size_t)NUM_NODES * 4);
    int*   packed  = (int*)  carve((size_t)NUM_EDGES * 4);   // 12.8 MB
    int*   src_srt = (int*)  carve((size_t)NUM_EDGES * 4);   // 12.8 MB
    float* yA      = (float*)carve(XBYTES);
    float* yB      = (float*)carve(XBYTES);
    float* outw    = (float*)carve(XBYTES);

    const float alpha = 1.0f / (NUM_LAYERS + 1);   // 0.25

    // ---- build exact dst-sorted CSR: chunked counting sort, zero global atomics
    chist_kernel<<<NCHUNK, 256, 0, stream>>>(e_dst, hist_g);
    bscan_kernel<<<(NBUCKETS * 64 + 255) / 256, 256, 0, stream>>>(hist_g, bcnt);
    scan_kernel<<<1, 1024, 0, stream>>>(bcnt, boffs);
    cscatter_kernel<<<NCHUNK, 256, 0, stream>>>(e_src, e_dst, boffs, hist_g, packed);
    lsort_kernel<<<NBUCKETS, 256, 0, stream>>>(boffs, packed, offs, src_srt, dis);
    prescale_kernel<<<2048, 256, 0, stream>>>((const float4*)emb, dis, (float4*)yA);

    // ---- 3 propagation layers (y-space), out-accumulation fused
    const int PROP_BLOCKS = (NUM_NODES * 64 + 255) / 256;
    prop_kernel<<<PROP_BLOCKS, 256, 0, stream>>>(offs, src_srt, dis, yA, yB, emb, outw, alpha, 0);
    prop_kernel<<<PROP_BLOCKS, 256, 0, stream>>>(offs, src_srt, dis, yB, yA, emb, outw, alpha, 1);
    prop_kernel<<<PROP_BLOCKS, 256, 0, stream>>>(offs, src_srt, dis, yA, yB, emb, outw, alpha, 2);

    // ---- scoring: 64 queries per 256-thread block (16 per wave)
    score_kernel<<<NUM_QUERY / 64, 256, 0, stream>>>(q_a, q_b, (const float4*)outw, out);
}